// Round 6
// baseline (169.235 us; speedup 1.0000x reference)
//
#include <hip/hip_runtime.h>

// IntDVF: scaling-and-squaring integration of a stationary velocity field.
// ddf = dvf / 2^7; repeat 7x: ddf = ddf + trilerp(ddf, grid + ddf)
// Volume: (B=2, D=128, H=128, W=128, C=3) float32, coords clamped to [0,127].
//
// Structure (R6): vectorized pack pass (f32 AoS -> fp16 8B/voxel, scale folded)
// then 7 gather steps on the fp16 field. Each step: 4 x-pair dwordx4 gathers
// per voxel (instruction floor at 8B/voxel); cost model = L1 line-visits per
// gather instr (~55 late-step) -> ~20us/step. XCD z-slab swizzle keeps each
// XCD's gather halo in its own L2. R5's fused f32-gather step 1 (46.8us)
// reverted: pack(~10us)+fp16 step(~20us) is cheaper.

#define M_   (1 << 21)          // 128^3 voxels per batch
#define NVOX (1 << 22)          // 2 batches
#define NBLK (NVOX / 256)       // 16384 blocks, %8 == 0

typedef _Float16 h4 __attribute__((ext_vector_type(4)));
typedef _Float16 h8 __attribute__((ext_vector_type(8)));
struct __attribute__((packed, aligned(8))) H8U { h8 v; };   // 16B load, 8B-aligned

// bijective block swizzle: XCD k (round-robin over blockIdx) gets the
// contiguous work-chunk [k*NBLK/8, (k+1)*NBLK/8)
__device__ __forceinline__ int swz_voxel() {
    const int wb = ((blockIdx.x & 7) * (NBLK / 8)) + (blockIdx.x >> 3);
    return wb * 256 + threadIdx.x;
}

// ---------- pack: f32 AoS12 -> fp16 8B/voxel (+ /128 scale), 4 vox/thread ----------
__global__ __launch_bounds__(256) void pack_k(const float* __restrict__ src,
                                              h8* __restrict__ dst) {
    const int t = blockIdx.x * blockDim.x + threadIdx.x;   // 0 .. NVOX/4-1
    const float s = 1.0f / 128.0f;
    const float4* s4 = (const float4*)src;
    const float4 a = s4[3 * t + 0];
    const float4 b = s4[3 * t + 1];
    const float4 c = s4[3 * t + 2];
    // voxels v..v+3: v0:(a.x,a.y,a.z) v1:(a.w,b.x,b.y) v2:(b.z,b.w,c.x) v3:(c.y,c.z,c.w)
    h8 lo = { (_Float16)(a.x * s), (_Float16)(a.y * s), (_Float16)(a.z * s), (_Float16)0.f,
              (_Float16)(a.w * s), (_Float16)(b.x * s), (_Float16)(b.y * s), (_Float16)0.f };
    h8 hi = { (_Float16)(b.z * s), (_Float16)(b.w * s), (_Float16)(c.x * s), (_Float16)0.f,
              (_Float16)(c.y * s), (_Float16)(c.z * s), (_Float16)(c.w * s), (_Float16)0.f };
    dst[2 * t + 0] = lo;      // two 16B stores
    dst[2 * t + 1] = hi;
}

// ---------- warp step: fp16 field -> fp16 field (AOS_OUT: -> f32 AoS, final) ----------
template <bool AOS_OUT>
__global__ __launch_bounds__(256) void step_k(const h4* __restrict__ src,
                                              h4* __restrict__ dst,
                                              float* __restrict__ daos) {
    const int idx = swz_voxel();
    const int x = idx & 127;
    const int y = (idx >> 7) & 127;
    const int z = (idx >> 14) & 127;
    const int bb = idx & M_;             // batch base (bit 21)

    const h4 c = src[idx];               // coalesced 8B center read
    const float v0 = (float)c[0];        // D (z) displacement
    const float v1 = (float)c[1];        // H (y)
    const float v2 = (float)c[2];        // W (x)

    const float cz = fminf(fmaxf((float)z + v0, 0.0f), 127.0f);
    const float cy = fminf(fmaxf((float)y + v1, 0.0f), 127.0f);
    const float cx = fminf(fmaxf((float)x + v2, 0.0f), 127.0f);

    const float fz = floorf(cz), fy = floorf(cy), fx = floorf(cx);
    const float wz = cz - fz, wy = cy - fy, wx = cx - fx;
    const int i0z = (int)fz, i0y = (int)fy, i0x = (int)fx;
    const int i1z = min(i0z + 1, 127);
    const int i1y = min(i0y + 1, 127);
    const float wz0 = 1.0f - wz, wy0 = 1.0f - wy, wx0 = 1.0f - wx;

    float o0 = 0.0f, o1 = 0.0f, o2 = 0.0f;
    #pragma unroll
    for (int b0 = 0; b0 < 2; ++b0) {
        const int   iz  = (b0 ? i1z : i0z) << 14;
        const float wwz = b0 ? wz : wz0;
        #pragma unroll
        for (int b1 = 0; b1 < 2; ++b1) {
            const int   iy  = (b1 ? i1y : i0y) << 7;
            const float w01 = wwz * (b1 ? wy : wy0);
            // one 16B load covers the x-pair (i0x, i0x+1). When i0x==127,
            // cx==127 so wx==0 and the garbage voxel gets weight exactly 0
            // (values finite: our own fp16 field or 0xAA poison, both finite).
            const H8U* p = (const H8U*)(src + (bb + (iz | iy) + i0x));
            const h8 q = p->v;
            const float wa = w01 * wx0, wb = w01 * wx;
            o0 += wa * (float)q[0] + wb * (float)q[4];
            o1 += wa * (float)q[1] + wb * (float)q[5];
            o2 += wa * (float)q[2] + wb * (float)q[6];
        }
    }

    const float r0 = v0 + o0, r1 = v1 + o1, r2 = v2 + o2;
    if (AOS_OUT) {
        float* d = daos + (size_t)idx * 3;
        d[0] = r0; d[1] = r1; d[2] = r2;
    } else {
        h4 r = { (_Float16)r0, (_Float16)r1, (_Float16)r2, (_Float16)0.f };
        dst[idx] = r;
    }
}

extern "C" void kernel_launch(void* const* d_in, const int* in_sizes, int n_in,
                              void* d_out, int out_size, void* d_ws, size_t ws_size,
                              hipStream_t stream) {
    const float* dvf = (const float*)d_in[0];
    float* out = (float*)d_out;

    // Two fp16 field buffers (NVOX * 8B = 33.5MB each):
    //   A = front of d_out (dead before the final f32 write), B = front of d_ws.
    // pack->B, s1 B->A, s2 A->B, s3 B->A, s4 A->B, s5 B->A, s6 A->B, s7 B->out.
    // Final step reads only B (ws) while overwriting d_out with f32 -- no alias.
    h4* A = (h4*)d_out;
    h4* B = (h4*)d_ws;

    const dim3 blk(256);
    const dim3 grd(NBLK);
    const dim3 grd4(NVOX / 4 / 256);

    pack_k<<<grd4, blk, 0, stream>>>(dvf, (h8*)B);                    // pack + scale
    step_k<false><<<grd, blk, 0, stream>>>(B, A, nullptr);            // s1
    step_k<false><<<grd, blk, 0, stream>>>(A, B, nullptr);            // s2
    step_k<false><<<grd, blk, 0, stream>>>(B, A, nullptr);            // s3
    step_k<false><<<grd, blk, 0, stream>>>(A, B, nullptr);            // s4
    step_k<false><<<grd, blk, 0, stream>>>(B, A, nullptr);            // s5
    step_k<false><<<grd, blk, 0, stream>>>(A, B, nullptr);            // s6
    step_k<true> <<<grd, blk, 0, stream>>>(B, nullptr, out);          // s7 -> f32 AoS
}

// Round 7
// 168.353 us; speedup vs baseline: 1.0052x; 1.0052x over previous
//
#include <hip/hip_runtime.h>

// IntDVF: scaling-and-squaring integration of a stationary velocity field.
// ddf = dvf / 2^7; repeat 7x: ddf = ddf + trilerp(ddf, grid + ddf)
// Volume: (B=2, D=128, H=128, W=128, C=3) float32, coords clamped to [0,127].
//
// Structure: LDS-coalesced pack pass (f32 AoS -> fp16 8B/voxel, scale folded),
// 7 gather steps on the fp16 field (4 x-pair dwordx4 gathers/voxel -- the
// instruction floor at 8B/voxel; late-step cost = ~1 L1 line-visit per lane
// per gather, the union bound for decorrelated floor indices), XCD z-slab
// swizzle for L2 locality, LDS-staged f32 AoS epilogue on the final step.
// R6 lesson: 12B/48B lane-stride AoS access costs ~48 line-visits/wave/instr
// -- always stage AoS conversions through LDS.

#define M_   (1 << 21)          // 128^3 voxels per batch
#define NVOX (1 << 22)          // 2 batches
#define NBLK (NVOX / 256)       // 16384 blocks, %8 == 0

typedef _Float16 h4 __attribute__((ext_vector_type(4)));
typedef _Float16 h8 __attribute__((ext_vector_type(8)));
struct __attribute__((packed, aligned(8))) H8U { h8 v; };   // 16B load, 8B-aligned

// bijective block swizzle: XCD k (round-robin over blockIdx) gets the
// contiguous work-chunk [k*NBLK/8, (k+1)*NBLK/8)
__device__ __forceinline__ int swz_block() {
    return ((blockIdx.x & 7) * (NBLK / 8)) + (blockIdx.x >> 3);
}

// ---------- pack: f32 AoS12 -> fp16 8B/voxel (+ /128 scale), LDS-coalesced ----------
// 1024 voxels/block: stage 768 float4 dense, re-read AoS from LDS.
__global__ __launch_bounds__(256) void pack_k(const float* __restrict__ src,
                                              h4* __restrict__ dst) {
    __shared__ float4 lds[768];
    const int tid = threadIdx.x;
    const size_t b4 = (size_t)blockIdx.x * 768;     // float4 base
    const float4* s4 = (const float4*)src;
    #pragma unroll
    for (int j = 0; j < 3; ++j)
        lds[j * 256 + tid] = s4[b4 + j * 256 + tid];    // dense coalesced
    __syncthreads();
    const float s = 1.0f / 128.0f;
    const float* lf = (const float*)lds;
    const int vb = blockIdx.x * 1024;               // voxel base
    #pragma unroll
    for (int k = 0; k < 4; ++k) {
        const int v = tid + 256 * k;
        const float a0 = lf[3 * v], a1 = lf[3 * v + 1], a2 = lf[3 * v + 2];
        h4 o = { (_Float16)(a0 * s), (_Float16)(a1 * s), (_Float16)(a2 * s), (_Float16)0.f };
        dst[vb + v] = o;                            // 8B coalesced
    }
}

// ---------- warp step: fp16 field -> fp16 field (AOS_OUT: -> f32 AoS, final) ----------
template <bool AOS_OUT>
__global__ __launch_bounds__(256) void step_k(const h4* __restrict__ src,
                                              h4* __restrict__ dst,
                                              float* __restrict__ daos) {
    const int tid = threadIdx.x;
    const int wb  = swz_block();
    const int idx = wb * 256 + tid;
    const int x = idx & 127;
    const int y = (idx >> 7) & 127;
    const int z = (idx >> 14) & 127;
    const int bb = idx & M_;             // batch base (bit 21)

    const h4 c = src[idx];               // coalesced 8B center read
    const float v0 = (float)c[0];        // D (z) displacement
    const float v1 = (float)c[1];        // H (y)
    const float v2 = (float)c[2];        // W (x)

    const float cz = fminf(fmaxf((float)z + v0, 0.0f), 127.0f);
    const float cy = fminf(fmaxf((float)y + v1, 0.0f), 127.0f);
    const float cx = fminf(fmaxf((float)x + v2, 0.0f), 127.0f);

    const float fz = floorf(cz), fy = floorf(cy), fx = floorf(cx);
    const float wz = cz - fz, wy = cy - fy, wx = cx - fx;
    const int i0z = (int)fz, i0y = (int)fy, i0x = (int)fx;
    const int i1z = min(i0z + 1, 127);
    const int i1y = min(i0y + 1, 127);
    const float wz0 = 1.0f - wz, wy0 = 1.0f - wy, wx0 = 1.0f - wx;

    float o0 = 0.0f, o1 = 0.0f, o2 = 0.0f;
    #pragma unroll
    for (int b0 = 0; b0 < 2; ++b0) {
        const int   iz  = (b0 ? i1z : i0z) << 14;
        const float wwz = b0 ? wz : wz0;
        #pragma unroll
        for (int b1 = 0; b1 < 2; ++b1) {
            const int   iy  = (b1 ? i1y : i0y) << 7;
            const float w01 = wwz * (b1 ? wy : wy0);
            // one 16B load covers the x-pair (i0x, i0x+1). When i0x==127,
            // cx==127 so wx==0 and the garbage voxel gets weight exactly 0
            // (values finite: our own fp16 field or 0xAA poison, both finite).
            const H8U* p = (const H8U*)(src + (bb + (iz | iy) + i0x));
            const h8 q = p->v;
            const float wa = w01 * wx0, wb = w01 * wx;
            o0 += wa * (float)q[0] + wb * (float)q[4];
            o1 += wa * (float)q[1] + wb * (float)q[5];
            o2 += wa * (float)q[2] + wb * (float)q[6];
        }
    }

    const float r0 = v0 + o0, r1 = v1 + o1, r2 = v2 + o2;
    if (AOS_OUT) {
        // LDS-staged f32 AoS epilogue: dense float4 stores
        __shared__ float lds[768];
        lds[3 * tid + 0] = r0;
        lds[3 * tid + 1] = r1;
        lds[3 * tid + 2] = r2;
        __syncthreads();
        float4* o4 = (float4*)daos + (size_t)wb * 192;
        if (tid < 192) o4[tid] = ((const float4*)lds)[tid];
    } else {
        h4 r = { (_Float16)r0, (_Float16)r1, (_Float16)r2, (_Float16)0.f };
        dst[idx] = r;
    }
}

extern "C" void kernel_launch(void* const* d_in, const int* in_sizes, int n_in,
                              void* d_out, int out_size, void* d_ws, size_t ws_size,
                              hipStream_t stream) {
    const float* dvf = (const float*)d_in[0];
    float* out = (float*)d_out;

    // Two fp16 field buffers (NVOX * 8B = 33.5MB each):
    //   A = front of d_out (dead before the final f32 write), B = front of d_ws.
    // pack->B, s1 B->A, s2 A->B, s3 B->A, s4 A->B, s5 B->A, s6 A->B, s7 B->out.
    // Final step reads only B (ws) while overwriting d_out with f32 -- no alias.
    h4* A = (h4*)d_out;
    h4* B = (h4*)d_ws;

    const dim3 blk(256);
    const dim3 grd(NBLK);
    const dim3 grdp(NVOX / 1024);

    pack_k<<<grdp, blk, 0, stream>>>(dvf, B);                         // pack + scale
    step_k<false><<<grd, blk, 0, stream>>>(B, A, nullptr);            // s1
    step_k<false><<<grd, blk, 0, stream>>>(A, B, nullptr);            // s2
    step_k<false><<<grd, blk, 0, stream>>>(B, A, nullptr);            // s3
    step_k<false><<<grd, blk, 0, stream>>>(A, B, nullptr);            // s4
    step_k<false><<<grd, blk, 0, stream>>>(B, A, nullptr);            // s5
    step_k<false><<<grd, blk, 0, stream>>>(A, B, nullptr);            // s6
    step_k<true> <<<grd, blk, 0, stream>>>(B, nullptr, out);          // s7 -> f32 AoS
}